// Round 16
// baseline (1299.219 us; speedup 1.0000x reference)
//
#include <hip/hip_runtime.h>

#define TSTEPS 2048
#define NBATCH 512
#define H1 64
#define H2 16

typedef _Float16 h2v __attribute__((ext_vector_type(2)));

__device__ __forceinline__ float fsig(float x) {
    return __builtin_amdgcn_rcpf(1.0f + __builtin_amdgcn_exp2f(-1.4426950408889634f * x));
}
__device__ __forceinline__ float ftanh(float x) {
    // tanh(x) = 1 - 2/(exp2(2x*log2e)+1); saturates correctly at +-inf
    return 1.0f - 2.0f * __builtin_amdgcn_rcpf(1.0f + __builtin_amdgcn_exp2f(2.8853900817779268f * x));
}
__device__ __forceinline__ float act(float x, float k2) {
    return k2 * fsig(k2 * x) - (k2 - 1.0f);
}

#if __has_builtin(__builtin_amdgcn_fdot2)
__device__ __forceinline__ float dot2(int wp, int hp, float acc) {
    return __builtin_amdgcn_fdot2(__builtin_bit_cast(h2v, wp),
                                  __builtin_bit_cast(h2v, hp), acc, false);
}
#else
__device__ __forceinline__ float dot2(int wp, int hp, float acc) {
    h2v a = __builtin_bit_cast(h2v, wp), b = __builtin_bit_cast(h2v, hp);
    return acc + (float)a.x * (float)b.x + (float)a.y * (float)b.y;
}
#endif

__device__ __forceinline__ int packh2(float a, float b) {
    h2v v; v.x = (_Float16)a; v.y = (_Float16)b;
    return __builtin_bit_cast(int, v);
}
template<int CTRL>
__device__ __forceinline__ float dpp_bcast(float v) {   // quad broadcast
    int r = __builtin_amdgcn_mov_dpp(__float_as_int(v), CTRL, 0xF, 0xF, true);
    return __int_as_float(r);
}
__device__ __forceinline__ int dpp_xor1_i(int v) {      // lane j <- lane j^1
    return __builtin_amdgcn_mov_dpp(v, 0xB1, 0xF, 0xF, true);
}

// ONE WAVE PER BATCH, ZERO BARRIERS, h-RECURRENCE THROUGH SGPRs.
// r15 verdict: weight-stream source (L2 vs LDS) is irrelevant (1175 vs 1173);
// no spills at VGPR=132. The remaining stall is the serial LDS round-trip of
// the recurrence (ds_write h1 -> ds_read h1, ~150+ cyc exposed at 1 wave/SIMD)
// AMPLIFIED by lgkmcnt being a single counter: waiting for the h-read also
// drains the 26 outstanding weight reads. Fix: h1/h2 never touch LDS --
// pack pairs via quad-DPP, v_readlane into SGPRs, and feed v_dot2's src1
// from SGPRs (1 SGPR operand is legal). The lgkm counter then carries ONLY
// independent weight streams (a full step of lookahead to hide them), and
// the recurrence chain is pure VALU. L1 chains split into 2 partials.
__global__ void __launch_bounds__(64, 1)
__attribute__((amdgpu_waves_per_eu(1, 1)))
lstm2_fused(const float* __restrict__ x,      // [512, 2048, 1]
            const float* __restrict__ w_ih1,  // [256, 1]
            const float* __restrict__ w_hh1,  // [256, 64]
            const float* __restrict__ b_ih1,  // [256]
            const float* __restrict__ b_hh1,  // [256]
            const float* __restrict__ w_ih2,  // [64, 64]
            const float* __restrict__ w_hh2,  // [64, 16]
            const float* __restrict__ b_ih2,  // [64]
            const float* __restrict__ b_hh2,  // [64]
            float* __restrict__ out)          // [512, 2048, 16]
{
    const int lane = threadIdx.x;     // 64 threads = 1 wave
    const int b    = blockIdx.x;      // 1 batch per block

    __shared__ int4  wlds[26][64];    // 26.6 KB streamed weights
    __shared__ float x_lds[TSTEPS];   // 8 KB
    __shared__ float ring[32][H2];    // 2 KB output ring

    // ---- stage x[b,:] ----
    {
        const float4* xs = (const float4*)(x + (size_t)b * TSTEPS);
        float4* xd = (float4*)x_lds;
        #pragma unroll
        for (int i = 0; i < 8; ++i) xd[lane + 64 * i] = xs[lane + 64 * i];
    }

    // ---- register-resident L1 weights: gates i (row lane), f (row 64+lane) ----
    int w1i[32], w1f[32];
    {
        const float* wri = w_hh1 + (size_t)lane * H1;
        const float* wrf = w_hh1 + (size_t)(H1 + lane) * H1;
        #pragma unroll
        for (int k = 0; k < 32; ++k) {
            w1i[k] = packh2(wri[2 * k], wri[2 * k + 1]);
            w1f[k] = packh2(wrf[2 * k], wrf[2 * k + 1]);
        }
    }
    // ---- LDS-streamed weights: w1 gate g (tq 0..7), gate o (tq 8..15),
    //      w2 (tq 16..23), wh2 (tq 24..25). Lane-private columns. ----
    const int m  = lane >> 2;
    const int g2 = lane & 3;
    const int r2 = g2 * H2 + m;
    {
        const float* wrg = w_hh1 + (size_t)(2 * H1 + lane) * H1;
        const float* wro = w_hh1 + (size_t)(3 * H1 + lane) * H1;
        const float* wr2 = w_ih2 + (size_t)r2 * H1;
        #pragma unroll
        for (int tq = 0; tq < 8; ++tq) {
            wlds[tq][lane] = make_int4(
                packh2(wrg[8*tq+0], wrg[8*tq+1]), packh2(wrg[8*tq+2], wrg[8*tq+3]),
                packh2(wrg[8*tq+4], wrg[8*tq+5]), packh2(wrg[8*tq+6], wrg[8*tq+7]));
            wlds[8 + tq][lane] = make_int4(
                packh2(wro[8*tq+0], wro[8*tq+1]), packh2(wro[8*tq+2], wro[8*tq+3]),
                packh2(wro[8*tq+4], wro[8*tq+5]), packh2(wro[8*tq+6], wro[8*tq+7]));
            wlds[16 + tq][lane] = make_int4(
                packh2(wr2[8*tq+0], wr2[8*tq+1]), packh2(wr2[8*tq+2], wr2[8*tq+3]),
                packh2(wr2[8*tq+4], wr2[8*tq+5]), packh2(wr2[8*tq+6], wr2[8*tq+7]));
        }
        const float* wrh = w_hh2 + (size_t)r2 * H2;
        wlds[24][lane] = make_int4(packh2(wrh[0], wrh[1]),  packh2(wrh[2], wrh[3]),
                                   packh2(wrh[4], wrh[5]),  packh2(wrh[6], wrh[7]));
        wlds[25][lane] = make_int4(packh2(wrh[8], wrh[9]),  packh2(wrh[10], wrh[11]),
                                   packh2(wrh[12], wrh[13]), packh2(wrh[14], wrh[15]));
    }

    // ---- per-gate scalars ----
    const float wxi = w_ih1[lane],        wxf = w_ih1[H1 + lane];
    const float wxg = w_ih1[2*H1 + lane], wxo = w_ih1[3*H1 + lane];
    const float bsi = b_ih1[lane] + b_hh1[lane];
    const float bsf = b_ih1[H1+lane] + b_hh1[H1+lane];
    const float bsg = b_ih1[2*H1+lane] + b_hh1[2*H1+lane];
    const float bso = b_ih1[3*H1+lane] + b_hh1[3*H1+lane];
    const float bs2 = b_ih2[r2] + b_hh2[r2];
    const float k22 = (g2 == 2) ? 2.0f : 1.0f;

    float c1 = 0.0f;
    float c2 = 0.0f;
    float* outb = out + (size_t)b * TSTEPS * H2;

    const int4* wl = &wlds[0][0];     // index tq*64 + lane

    // h state broadcast in SGPRs (uniform values via readlane)
    int sh[32];                       // h1(p-1) packed pairs
    int s2h[8];                       // h2(p-2) packed pairs
    #pragma unroll
    for (int i = 0; i < 32; ++i) sh[i] = 0;
    #pragma unroll
    for (int i = 0; i < 8; ++i)  s2h[i] = 0;

    for (int p = 0; p <= TSTEPS; ++p) {
        // ---- output flush: every 16 steps, slots written 16-31 steps ago ----
        const int tau_f = p - 1;
        if (tau_f >= 31 && (tau_f & 15) == 15) {
            const int tau0 = (tau_f & ~15) - 16;
            const int tt = tau0 + (lane >> 2), ch0 = (lane & 3) * 4;
            float4 v = *(const float4*)&ring[tt & 31][ch0];
            *(float4*)(outb + (size_t)tt * H2 + ch0) = v;      // 1 KB coalesced
        }

        // ---- gate accumulators (L1 split into 2 partials per gate) ----
        const float xv = x_lds[p & (TSTEPS - 1)];
        float aiA = bsi + wxi * xv, aiB = 0.f;
        float afA = bsf + wxf * xv, afB = 0.f;
        float agA = bsg + wxg * xv, agB = 0.f;
        float aoA = bso + wxo * xv, aoB = 0.f;
        float a0 = bs2, a1 = 0.f, a2a = 0.f, a3 = 0.f;
        int4 vh0, vh1;

        #pragma unroll
        for (int c = 0; c < 4; ++c) {
            int4 cg  = wl[(2*c)      * 64 + lane];
            int4 cg2 = wl[(2*c + 1)  * 64 + lane];
            int4 co  = wl[(8 + 2*c)  * 64 + lane];
            int4 co2 = wl[(9 + 2*c)  * 64 + lane];
            int4 cu  = wl[(16 + 2*c) * 64 + lane];
            int4 cu2 = wl[(17 + 2*c) * 64 + lane];
            if (c == 2) { vh0 = wl[24 * 64 + lane]; vh1 = wl[25 * 64 + lane]; }
            float* pi = (c < 2) ? &aiA : &aiB;
            float* pf = (c < 2) ? &afA : &afB;
            float* pg = (c < 2) ? &agA : &agB;
            float* po = (c < 2) ? &aoA : &aoB;

            *pi = dot2(w1i[8*c+0], sh[8*c+0], *pi); *pi = dot2(w1i[8*c+1], sh[8*c+1], *pi);
            *pi = dot2(w1i[8*c+2], sh[8*c+2], *pi); *pi = dot2(w1i[8*c+3], sh[8*c+3], *pi);
            *pi = dot2(w1i[8*c+4], sh[8*c+4], *pi); *pi = dot2(w1i[8*c+5], sh[8*c+5], *pi);
            *pi = dot2(w1i[8*c+6], sh[8*c+6], *pi); *pi = dot2(w1i[8*c+7], sh[8*c+7], *pi);

            *pf = dot2(w1f[8*c+0], sh[8*c+0], *pf); *pf = dot2(w1f[8*c+1], sh[8*c+1], *pf);
            *pf = dot2(w1f[8*c+2], sh[8*c+2], *pf); *pf = dot2(w1f[8*c+3], sh[8*c+3], *pf);
            *pf = dot2(w1f[8*c+4], sh[8*c+4], *pf); *pf = dot2(w1f[8*c+5], sh[8*c+5], *pf);
            *pf = dot2(w1f[8*c+6], sh[8*c+6], *pf); *pf = dot2(w1f[8*c+7], sh[8*c+7], *pf);

            *pg = dot2(cg.x,  sh[8*c+0], *pg); *pg = dot2(cg.y,  sh[8*c+1], *pg);
            *pg = dot2(cg.z,  sh[8*c+2], *pg); *pg = dot2(cg.w,  sh[8*c+3], *pg);
            *pg = dot2(cg2.x, sh[8*c+4], *pg); *pg = dot2(cg2.y, sh[8*c+5], *pg);
            *pg = dot2(cg2.z, sh[8*c+6], *pg); *pg = dot2(cg2.w, sh[8*c+7], *pg);

            *po = dot2(co.x,  sh[8*c+0], *po); *po = dot2(co.y,  sh[8*c+1], *po);
            *po = dot2(co.z,  sh[8*c+2], *po); *po = dot2(co.w,  sh[8*c+3], *po);
            *po = dot2(co2.x, sh[8*c+4], *po); *po = dot2(co2.y, sh[8*c+5], *po);
            *po = dot2(co2.z, sh[8*c+6], *po); *po = dot2(co2.w, sh[8*c+7], *po);

            a0  = dot2(cu.x,  sh[8*c+0], a0);  a1  = dot2(cu.y,  sh[8*c+1], a1);
            a2a = dot2(cu.z,  sh[8*c+2], a2a); a3  = dot2(cu.w,  sh[8*c+3], a3);
            a0  = dot2(cu2.x, sh[8*c+4], a0);  a1  = dot2(cu2.y, sh[8*c+5], a1);
            a2a = dot2(cu2.z, sh[8*c+6], a2a); a3  = dot2(cu2.w, sh[8*c+7], a3);
        }

        // ===== Layer 1 finish, timestep p; rebuild sh via DPP+readlane =====
        if (p < TSTEPS) {
            float gi = fsig(aiA + aiB), gf = fsig(afA + afB);
            float gg = ftanh(agA + agB), go = fsig(aoA + aoB);
            c1 = gf * c1 + gi * gg;
            float h1n = go * ftanh(c1);
            h2v hv; hv.x = (_Float16)h1n; hv.y = (_Float16)0.0f;
            int h1u = __builtin_bit_cast(int, hv) & 0xFFFF;
            int nb  = dpp_xor1_i(h1u);
            int packed = h1u | (nb << 16);        // even lane j: h[j]|h[j+1]<<16
            #pragma unroll
            for (int i = 0; i < 32; ++i)
                sh[i] = __builtin_amdgcn_readlane(packed, 2 * i);
        }

        // ===== Layer 2 finish, timestep p-1; rebuild s2h =====
        if (p >= 1) {
            a0  = dot2(vh0.x, s2h[0], a0);  a1  = dot2(vh0.y, s2h[1], a1);
            a2a = dot2(vh0.z, s2h[2], a2a); a3  = dot2(vh0.w, s2h[3], a3);
            a0  = dot2(vh1.x, s2h[4], a0);  a1  = dot2(vh1.y, s2h[5], a1);
            a2a = dot2(vh1.z, s2h[6], a2a); a3  = dot2(vh1.w, s2h[7], a3);
            float av = act((a0 + a1) + (a2a + a3), k22);
            float gi = dpp_bcast<0x00>(av);
            float gf = dpp_bcast<0x55>(av);
            float gg = dpp_bcast<0xAA>(av);
            float go = dpp_bcast<0xFF>(av);
            c2 = gf * c2 + gi * gg;
            float h2n = go * ftanh(c2);
            h2v h2p; h2p.x = (_Float16)h2n; h2p.y = (_Float16)0.0f;
            int h2u = __builtin_bit_cast(int, h2p) & 0xFFFF;
            #pragma unroll
            for (int k = 0; k < 8; ++k) {
                int lo = __builtin_amdgcn_readlane(h2u, 8 * k);       // channel 2k
                int hi = __builtin_amdgcn_readlane(h2u, 8 * k + 4);   // channel 2k+1
                s2h[k] = lo | (hi << 16);
            }
            if (g2 == 0) ring[(p - 1) & 31][m] = h2n;
        }
    }

    // ---- tail flush: timesteps 2032..2047 (same wave -> FIFO safe) ----
    {
        const int tt = 2032 + (lane >> 2), ch0 = (lane & 3) * 4;
        float4 v = *(const float4*)&ring[tt & 31][ch0];
        *(float4*)(outb + (size_t)tt * H2 + ch0) = v;
    }
}

extern "C" void kernel_launch(void* const* d_in, const int* in_sizes, int n_in,
                              void* d_out, int out_size, void* d_ws, size_t ws_size,
                              hipStream_t stream) {
    const float* x     = (const float*)d_in[0];
    const float* w_ih1 = (const float*)d_in[1];
    const float* w_hh1 = (const float*)d_in[2];
    const float* b_ih1 = (const float*)d_in[3];
    const float* b_hh1 = (const float*)d_in[4];
    const float* w_ih2 = (const float*)d_in[5];
    const float* w_hh2 = (const float*)d_in[6];
    const float* b_ih2 = (const float*)d_in[7];
    const float* b_hh2 = (const float*)d_in[8];
    float* out = (float*)d_out;

    lstm2_fused<<<NBATCH, 64, 0, stream>>>(x, w_ih1, w_hh1, b_ih1, b_hh1,
                                           w_ih2, w_hh2, b_ih2, b_hh2, out);
}